// Round 7
// baseline (157.058 us; speedup 1.0000x reference)
//
#include <hip/hip_runtime.h>
#include <hip/hip_bf16.h>

#define TPB 512  // 8 waves
#define BM 32
#define NROW 32768
#define NBLK (NROW / BM)
#define VV 1024
#define KD 256
#define TT 2048

#define LP_OFF 2L
#define ZQ_OFF (2L + 33554432L)
#define EM_OFF (33554434L + 8388608L)

// ws layout (floats)
#define WS_HIST 0
#define WS_CSUM 1024
#define WS_SSUM 2048
#define WS_MSUM 3072
#define WS_E8 4096                // bf16 e, 512 KB: [w][s][nt][g][lm] x 16B
#define WS_Z8G (4096 + 131072)    // bf16 z, 16 MB: [blk][oct][row] x 16B
#define WS_NEED_E ((size_t)WS_Z8G * 4)
#define WS_NEED_Z ((size_t)WS_Z8G * 4 + (size_t)NROW * KD * 2)

typedef __attribute__((ext_vector_type(8))) short bf16x8;
typedef __attribute__((ext_vector_type(4))) float f32x4;

__device__ __forceinline__ void gl_lds16(const float* g, float* l) {
  __builtin_amdgcn_global_load_lds(
      (const __attribute__((address_space(1))) void*)g,
      (__attribute__((address_space(3))) void*)l, 16, 0, 0);
}

__device__ __forceinline__ unsigned short f2bf(float x) {  // RNE
  unsigned u = __float_as_uint(x);
  unsigned r = ((u >> 16) & 1u) + 0x7FFFu;
  return (unsigned short)((u + r) >> 16);
}

__device__ __forceinline__ unsigned foldf(float v) {  // order-preserving
  unsigned b = __float_as_uint(v);
  return b ^ ((unsigned)((int)b >> 31) | 0x80000000u);
}
__device__ __forceinline__ float unfoldf(unsigned k) {
  unsigned s = (unsigned)((int)k >> 31);
  return __uint_as_float(k ^ (0x80000000u | (~s & 0x7FFFFFFFu)));
}

__device__ __forceinline__ int4 pack8(const float* p) {
  float4 a = *(const float4*)p;
  float4 b = *(const float4*)(p + 4);
  int4 pk;
  pk.x = f2bf(a.x) | ((unsigned)f2bf(a.y) << 16);
  pk.y = f2bf(a.z) | ((unsigned)f2bf(a.w) << 16);
  pk.z = f2bf(b.x) | ((unsigned)f2bf(b.y) << 16);
  pk.w = f2bf(b.z) | ((unsigned)f2bf(b.w) << 16);
  return pk;
}

// do_z=1: t<1048576 -> z8g unit t (blk,oct,row); rest -> e8.
__global__ __launch_bounds__(256) void tok_prep(
    const float* __restrict__ z, const float* __restrict__ cw,
    unsigned short* __restrict__ e8, unsigned short* __restrict__ z8g,
    int do_z) {
  int t = blockIdx.x * 256 + threadIdx.x;
  if (do_z && t < 1048576) {
    int blk = t >> 10, oct = (t >> 5) & 31, row = t & 31;
    *(int4*)(z8g + ((size_t)t << 3)) =
        pack8(z + ((size_t)((blk << 5) + row) << 8) + (oct << 3));
    return;
  }
  int t2 = do_z ? t - 1048576 : t;
  if (t2 >= 32768) return;
  int o = t2 >> 10, n = t2 & 1023;  // oct, col
  int U = ((n >> 7) << 12) + ((o >> 2) << 9) + (((n >> 4) & 7) << 6) +
          ((o & 3) << 4) + (n & 15);  // [w][s][nt][g][lm]
  // e8[col n] = bf16(e[n][8o..8o+7]) = cw row (1+n)  -- R6 bug was +KD here
  *(int4*)(e8 + ((size_t)U << 3)) =
      pack8(cw + ((size_t)(1 + n) << 8) + (o << 3));
}

// MODE 2: A-fragments from global z8g. MODE 1: converted in LDS.
template <int MODE>
__global__ __launch_bounds__(TPB, 2) void tok_mfma(
    const float* __restrict__ z, const float* __restrict__ mask,
    const float* __restrict__ cw, const unsigned short* __restrict__ e8,
    const unsigned short* __restrict__ z8g, float* __restrict__ out,
    float* __restrict__ ws) {
  __shared__ __align__(16) float z_s[BM][KD + 1];  // +1 pad
  __shared__ __align__(16) unsigned char upool[MODE == 1 ? 16384 : 4608];
  __shared__ float mask_s[BM];
  // epilogue overlays (upool reused after main loop; MODE1 A-frags live there
  // during the loop -> extra barrier before phase1)
  unsigned(*wkey)[2][33] = (unsigned(*)[2][33])upool;          // 2112 B
  float(*wsum)[33] = (float(*)[33])(upool + 2112);             // 1056 B
  float* lse_s = (float*)(upool + 3168);                       // 128 B
  float(*exv_s)[4] = (float(*)[4])(upool + 3296);              // 512 B
  int(*exi_s)[4] = (int(*)[4])(upool + 3808);                  // 512 B
  int* argi = (int*)(upool + 4320);                            // 128 B
  float* cred = (float*)(upool + 4448);                        // 32 B
  float* sred = (float*)(upool + 4480);                        // 32 B

  const int tid = threadIdx.x;
  const int lane = tid & 63;
  const int w = tid >> 6;   // 0..7
  const int g = lane >> 4;  // 0..3
  const int lm = lane & 15;
  const int c0 = w << 7;  // wave's 128-col base
  const int n0 = blockIdx.x * BM;

  // ---- fire-and-forget: z fp32 -> LDS (consumed only at E4B/E5) ----
#pragma unroll
  for (int i = 0; i < 4; ++i) {
    int row = (w << 2) + i;
    gl_lds16(&z[(size_t)(n0 + row) * KD + (lane << 2)], &z_s[row][0]);
  }
  if (tid < BM) mask_s[tid] = mask[n0 + tid];

  if constexpr (MODE == 1) {  // in-LDS bf16 conversion (fallback path)
    __syncthreads();
#pragma unroll
    for (int i = 0; i < 2; ++i) {
      int c = (i << 9) + tid;
      int oct = c >> 5, row = c & 31;
      *(int4*)&upool[((oct << 5) + row) << 4] = pack8(&z_s[row][oct << 3]);
    }
    __syncthreads();
  }

  // ---- MFMA main loop: depth-2 rotating prefetch, no barriers ----
  const bf16x8* Ap = (MODE == 2)
                         ? ((const bf16x8*)z8g + ((size_t)blockIdx.x << 10))
                         : (const bf16x8*)upool;
  const bf16x8* Bp = (const bf16x8*)e8 + ((w << 12) + (g << 4) + lm);
  f32x4 accA[8], accB[8];
  const f32x4 zz = {0.f, 0.f, 0.f, 0.f};
#pragma unroll
  for (int nt = 0; nt < 8; ++nt) { accA[nt] = zz; accB[nt] = zz; }
  bf16x8 Br[3][8];
  bf16x8 Ar[3][2];
#pragma unroll
  for (int p = 0; p < 2; ++p) {
#pragma unroll
    for (int nt = 0; nt < 8; ++nt) Br[p][nt] = Bp[(p << 9) + (nt << 6)];
    Ar[p][0] = Ap[(((p << 2) + g) << 5) + lm];
    Ar[p][1] = Ap[(((p << 2) + g) << 5) + 16 + lm];
  }
#pragma unroll
  for (int s = 0; s < 8; ++s) {
    const int cs = s % 3, ns = (s + 2) % 3;
    if (s < 6) {
#pragma unroll
      for (int nt = 0; nt < 8; ++nt)
        Br[ns][nt] = Bp[((s + 2) << 9) + (nt << 6)];
      Ar[ns][0] = Ap[((((s + 2) << 2) + g) << 5) + lm];
      Ar[ns][1] = Ap[((((s + 2) << 2) + g) << 5) + 16 + lm];
    }
#pragma unroll
    for (int nt = 0; nt < 8; ++nt) {
      accA[nt] =
          __builtin_amdgcn_mfma_f32_16x16x32_bf16(Ar[cs][0], Br[cs][nt], accA[nt], 0, 0, 0);
      accB[nt] =
          __builtin_amdgcn_mfma_f32_16x16x32_bf16(Ar[cs][1], Br[cs][nt], accB[nt], 0, 0, 0);
    }
  }

  if constexpr (MODE == 1) __syncthreads();  // A-frag reads done before overlay

  // D layout: row = mt*16 + g*4 + j, col = c0 + nt*16 + lm
  unsigned colpack[8];
#pragma unroll
  for (int nt = 0; nt < 8; ++nt)
    colpack[nt] = 1023u - (unsigned)(c0 + (nt << 4) + lm);

  // ---- phase1: per-wave top-2 keys + wave-local exp-sum (one pass) ----
  auto phase1 = [&](f32x4(&ac)[8], int mt) {
#pragma unroll
    for (int j = 0; j < 4; ++j) {
      const int r = (mt << 4) + (g << 2) + j;
      unsigned cur[8];
#pragma unroll
      for (int nt = 0; nt < 8; ++nt)
        cur[nt] = (foldf(ac[nt][j]) & 0xFFFFFC00u) | colpack[nt];
      unsigned k1 = cur[0];
#pragma unroll
      for (int nt = 1; nt < 8; ++nt) k1 = k1 > cur[nt] ? k1 : cur[nt];
#pragma unroll
      for (int d = 1; d <= 8; d <<= 1) {
        unsigned o2 = __shfl_xor(k1, d);
        k1 = k1 > o2 ? k1 : o2;
      }
      const float mw = unfoldf(k1 & 0xFFFFFC00u);  // wave-local max (trunc)
      float sum = 0.f;
#pragma unroll
      for (int nt = 0; nt < 8; ++nt) sum += __expf(ac[nt][j] - mw);
#pragma unroll
      for (int d = 1; d <= 8; d <<= 1) sum += __shfl_xor(sum, d);
#pragma unroll
      for (int nt = 0; nt < 8; ++nt)
        if (cur[nt] == k1) cur[nt] = 0u;
      unsigned k2 = cur[0];
#pragma unroll
      for (int nt = 1; nt < 8; ++nt) k2 = k2 > cur[nt] ? k2 : cur[nt];
#pragma unroll
      for (int d = 1; d <= 8; d <<= 1) {
        unsigned o2 = __shfl_xor(k2, d);
        k2 = k2 > o2 ? k2 : o2;
      }
      if (lm == 0) {
        wkey[w][0][r] = k1;
        wkey[w][1][r] = k2;
        wsum[w][r] = sum;
      }
    }
  };
  phase1(accA, 0);
  phase1(accB, 1);
  __syncthreads();

  // ---- row stats: global top-4, lse (32 threads) ----
  if (tid < 32) {
    const int r = tid;
    unsigned best[4] = {0u, 0u, 0u, 0u};
#pragma unroll
    for (int w2 = 0; w2 < 8; ++w2)
#pragma unroll
      for (int k = 0; k < 2; ++k) {
        unsigned x = wkey[w2][k][r];
#pragma unroll
        for (int q = 0; q < 4; ++q) {
          unsigned mx = x > best[q] ? x : best[q];
          unsigned mn = x > best[q] ? best[q] : x;
          best[q] = mx;
          x = mn;
        }
      }
    const float M = unfoldf(best[0] & 0xFFFFFC00u);
    float S = 0.f;
#pragma unroll
    for (int w2 = 0; w2 < 8; ++w2)
      S += wsum[w2][r] * __expf(unfoldf(wkey[w2][0][r] & 0xFFFFFC00u) - M);
    lse_s[r] = M + __logf(S);
#pragma unroll
    for (int q = 0; q < 4; ++q) exi_s[r][q] = (int)(1023u - (best[q] & 0x3FFu));
  }
  __syncthreads();

  // ---- E4B: exact fp32 dots, 4 cand x 4 rows per wave (4 lanes/dot) ----
  {
    const int row = (w << 2) + (lane >> 4);
    const int cd = (lane >> 2) & 3;
    const int seg = lane & 3;  // 64-float segment
    const int cand = exi_s[row][cd];
    const float* er = cw + (size_t)(1 + cand) * KD + (seg << 6);
    const float* zr = &z_s[row][seg << 6];
    float s = 0.f;
#pragma unroll
    for (int i2 = 0; i2 < 16; ++i2) {
      float4 a4 = *(const float4*)(zr + (i2 << 2));
      float4 b4 = *(const float4*)(er + (i2 << 2));
      s += a4.x * b4.x + a4.y * b4.y + a4.z * b4.z + a4.w * b4.w;
    }
    s += __shfl_xor(s, 1);
    s += __shfl_xor(s, 2);
    if (seg == 0) exv_s[row][cd] = s;
  }
  __syncthreads();

  // ---- final argmax (exact, first-index tiebreak) + histogram ----
  if (tid < 32) {
    const int row = tid;
    float bv = exv_s[row][0];
    int bi = exi_s[row][0];
#pragma unroll
    for (int c = 1; c < 4; ++c) {
      float v = exv_s[row][c];
      int ci = exi_s[row][c];
      if (v > bv || (v == bv && ci < bi)) { bv = v; bi = ci; }
    }
    argi[row] = bi;
    atomicAdd(&ws[WS_HIST + bi], mask_s[row]);  // mask=1.0 adds: exact
  }
  __syncthreads();

  // ---- E5: losses (keep gathered e rows in regs for the final store) ----
  float csum = 0.f, ssum = 0.f;
  float4 evs[4];
  const bool has_prev = (n0 % TT) != 0;
#pragma unroll
  for (int i = 0; i < 4; ++i) {
    const int r = (i << 3) + w;
    const int c4 = lane << 2;
    const int idx = argi[r];
    const float4 ev = *(const float4*)&cw[(size_t)(1 + idx) * KD + c4];
    evs[i] = ev;
    const float4 zv = *(const float4*)&z_s[r][c4];
    const float mk = mask_s[r];
    float dx = zv.x - ev.x, dy = zv.y - ev.y, dz2 = zv.z - ev.z,
          dw = zv.w - ev.w;
    csum += mk * (dx * dx + dy * dy + dz2 * dz2 + dw * dw);
    if (r > 0) {
      const float4 pv = *(const float4*)&z_s[r - 1][c4];
      float ax = zv.x - pv.x, ay = zv.y - pv.y, az = zv.z - pv.z,
            aw = zv.w - pv.w;
      ssum += mk * (ax * ax + ay * ay + az * az + aw * aw);
    } else if (has_prev) {
      const float4 pv = *(const float4*)&z[(size_t)(n0 - 1) * KD + c4];
      float ax = zv.x - pv.x, ay = zv.y - pv.y, az = zv.z - pv.z,
            aw = zv.w - pv.w;
      ssum += mk * (ax * ax + ay * ay + az * az + aw * aw);
    }
  }
#pragma unroll
  for (int d = 1; d <= 32; d <<= 1) {
    csum += __shfl_xor(csum, d);
    ssum += __shfl_xor(ssum, d);
  }
  if (lane == 0) { cred[w] = csum; sred[w] = ssum; }
  __syncthreads();
  if (tid == 0) {
    float cs = 0.f, ss2 = 0.f;
#pragma unroll
    for (int i = 0; i < 8; ++i) { cs += cred[i]; ss2 += sred[i]; }
    ws[WS_CSUM + blockIdx.x] = cs;
    ws[WS_SSUM + blockIdx.x] = ss2;
    float ms = 0.f;
    for (int r2 = 0; r2 < BM; ++r2) ms += mask_s[r2];
    ws[WS_MSUM + blockIdx.x] = ms;
  }

  // ---- stores dead-last: z_q then log_probs; no barriers after ----
#pragma unroll
  for (int i = 0; i < 4; ++i) {
    const int r = (i << 3) + w;
    *(float4*)&out[ZQ_OFF + (size_t)(n0 + r) * KD + (lane << 2)] = evs[i];
  }
  auto phase3 = [&](f32x4(&ac)[8], int mt) {
#pragma unroll
    for (int j = 0; j < 4; ++j) {
      const int r = (mt << 4) + (g << 2) + j;
      const float lse = lse_s[r];
      size_t base = LP_OFF + (size_t)(n0 + r) * VV;
#pragma unroll
      for (int nt = 0; nt < 8; ++nt)
        out[base + c0 + (nt << 4) + lm] = ac[nt][j] - lse;
    }
  };
  phase3(accA, 0);
  phase3(accB, 1);
}

// ---------- fp32 fallback if ws too small ----------
__global__ __launch_bounds__(256, 2) void tok_fb(
    const float* __restrict__ z, const float* __restrict__ mask,
    const float* __restrict__ cw, float* __restrict__ out,
    float* __restrict__ ws) {
  __shared__ __align__(16) float z_s[BM][KD];
  __shared__ int argi_s[BM];
  __shared__ float cred[4], sred[4];
  const int tid = threadIdx.x;
  const int lane = tid & 63;
  const int wave = tid >> 6;
  const int n0 = blockIdx.x * BM;
  const float* e = cw + KD;
#pragma unroll
  for (int i = 0; i < 8; ++i) {
    int seg = wave * 8 + i;
    gl_lds16(&z[(size_t)(n0 + seg) * KD + lane * 4], &z_s[seg][0]);
  }
  __syncthreads();
  float acc[8][16];
#pragma unroll
  for (int r = 0; r < 8; ++r)
#pragma unroll
    for (int m = 0; m < 16; ++m) acc[r][m] = 0.f;
#pragma unroll 1
  for (int i = 0; i < 64; ++i) {
    float4 ef[16];
#pragma unroll
    for (int m = 0; m < 16; ++m)
      ef[m] = *(const float4*)&e[(size_t)((m << 6) + lane) * KD + (i << 2)];
    float4 zf[8];
#pragma unroll
    for (int rr = 0; rr < 8; ++rr)
      zf[rr] = *(const float4*)&z_s[(wave << 3) + rr][i << 2];
#pragma unroll
    for (int m = 0; m < 16; ++m)
#pragma unroll
      for (int rr = 0; rr < 8; ++rr)
        acc[rr][m] += zf[rr].x * ef[m].x + zf[rr].y * ef[m].y +
                      zf[rr].z * ef[m].z + zf[rr].w * ef[m].w;
  }
  const int rowbase = wave << 3;
#pragma unroll
  for (int rr = 0; rr < 8; ++rr) {
    float mv = acc[rr][0];
    int mc = lane;
#pragma unroll
    for (int m = 1; m < 16; ++m) {
      float v = acc[rr][m];
      int c = (m << 6) + lane;
      bool tk = v > mv;
      mc = tk ? c : mc;
      mv = tk ? v : mv;
    }
#pragma unroll
    for (int d = 32; d >= 1; d >>= 1) {
      float ov = __shfl_xor(mv, d);
      int oc = __shfl_xor(mc, d);
      bool tk = (ov > mv) || (ov == mv && oc < mc);
      mv = tk ? ov : mv;
      mc = tk ? oc : mc;
    }
    float sum = 0.f;
#pragma unroll
    for (int m = 0; m < 16; ++m) sum += __expf(acc[rr][m] - mv);
#pragma unroll
    for (int d = 32; d >= 1; d >>= 1) sum += __shfl_xor(sum, d);
    float lse = mv + __logf(sum);
    size_t base = LP_OFF + (size_t)(n0 + rowbase + rr) * VV;
#pragma unroll
    for (int m = 0; m < 16; ++m) out[base + (m << 6) + lane] = acc[rr][m] - lse;
    if (lane == 0) {
      argi_s[rowbase + rr] = mc;
      atomicAdd(&ws[WS_HIST + mc], mask[n0 + rowbase + rr]);
    }
  }
  __syncthreads();
  float csum = 0.f, ssum = 0.f;
  const bool has_prev = (n0 % TT) != 0;
#pragma unroll
  for (int i = 0; i < 8; ++i) {
    int q = i * 256 + tid;
    int r = q >> 6;
    int c4 = (q & 63) << 2;
    int idx = argi_s[r];
    const float4 ev = *(const float4*)&e[(size_t)idx * KD + c4];
    const float4 zv = *(const float4*)&z_s[r][c4];
    *(float4*)&out[ZQ_OFF + (size_t)(n0 + r) * KD + c4] = ev;
    float mk = mask[n0 + r];
    float dx = zv.x - ev.x, dy = zv.y - ev.y, dz2 = zv.z - ev.z, dw = zv.w - ev.w;
    csum += mk * (dx * dx + dy * dy + dz2 * dz2 + dw * dw);
    if (r > 0) {
      const float4 pv = *(const float4*)&z_s[r - 1][c4];
      float ax = zv.x - pv.x, ay = zv.y - pv.y, az = zv.z - pv.z, aw = zv.w - pv.w;
      ssum += mk * (ax * ax + ay * ay + az * az + aw * aw);
    } else if (has_prev) {
      const float4 pv = *(const float4*)&z[(size_t)(n0 - 1) * KD + c4];
      float ax = zv.x - pv.x, ay = zv.y - pv.y, az = zv.z - pv.z, aw = zv.w - pv.w;
      ssum += mk * (ax * ax + ay * ay + az * az + aw * aw);
    }
  }
#pragma unroll
  for (int d = 32; d >= 1; d >>= 1) {
    csum += __shfl_xor(csum, d);
    ssum += __shfl_xor(ssum, d);
  }
  if (lane == 0) { cred[wave] = csum; sred[wave] = ssum; }
  __syncthreads();
  if (tid == 0) {
    ws[WS_CSUM + blockIdx.x] = cred[0] + cred[1] + cred[2] + cred[3];
    ws[WS_SSUM + blockIdx.x] = sred[0] + sred[1] + sred[2] + sred[3];
    float ms = 0.f;
    for (int r2 = 0; r2 < BM; ++r2) ms += mask[n0 + r2];
    ws[WS_MSUM + blockIdx.x] = ms;
  }
}

__global__ __launch_bounds__(1024) void tok_final(const float* __restrict__ ws,
                                                  float* __restrict__ out) {
  const int t = threadIdx.x;
  const int lane = t & 63, w = t >> 6;
  __shared__ float red[16];
  auto blockReduce = [&](float v) -> float {
#pragma unroll
    for (int d = 32; d >= 1; d >>= 1) v += __shfl_xor(v, d);
    __syncthreads();
    if (lane == 0) red[w] = v;
    __syncthreads();
    float s = 0.f;
#pragma unroll
    for (int i = 0; i < 16; ++i) s += red[i];
    return s;
  };
  float Mtot = blockReduce(ws[WS_MSUM + t]);
  float Ctot = blockReduce(ws[WS_CSUM + t]);
  float Stot = blockReduce(ws[WS_SSUM + t]);
  float prob = ws[WS_HIST + t] / Mtot;
  float psum = blockReduce(prob);
  out[EM_OFF + t] = prob / psum;
  if (t == 0) {
    float vc = Mtot * (float)KD;
    out[0] = Stot / vc;  // smoothness_loss
    out[1] = Ctot / vc;  // commitment_loss
  }
}

extern "C" void kernel_launch(void* const* d_in, const int* in_sizes, int n_in,
                              void* d_out, int out_size, void* d_ws,
                              size_t ws_size, hipStream_t stream) {
  const float* z = (const float*)d_in[0];
  const float* mask = (const float*)d_in[1];
  const float* cw = (const float*)d_in[2];
  float* out = (float*)d_out;
  float* ws = (float*)d_ws;
  hipMemsetAsync(ws, 0, 1024 * sizeof(float), stream);  // histogram zeros
  unsigned short* e8 = (unsigned short*)(ws + WS_E8);
  unsigned short* z8g = (unsigned short*)(ws + WS_Z8G);
  if (ws_size >= WS_NEED_Z) {
    tok_prep<<<4224, 256, 0, stream>>>(z, cw, e8, z8g, 1);
    tok_mfma<2><<<NBLK, TPB, 0, stream>>>(z, mask, cw, e8, z8g, out, ws);
  } else if (ws_size >= WS_NEED_E) {
    tok_prep<<<128, 256, 0, stream>>>(z, cw, e8, nullptr, 0);
    tok_mfma<1><<<NBLK, TPB, 0, stream>>>(z, mask, cw, e8, nullptr, out, ws);
  } else {
    tok_fb<<<NBLK, 256, 0, stream>>>(z, mask, cw, out, ws);
  }
  tok_final<<<1, 1024, 0, stream>>>(ws, out);
}

// Round 8
// 122.892 us; speedup vs baseline: 1.2780x; 1.2780x over previous
//
#include <hip/hip_runtime.h>
#include <hip/hip_bf16.h>

#define TPB 512  // 8 waves
#define BM 32
#define NROW 32768
#define NBLK (NROW / BM)
#define VV 1024
#define KD 256
#define TT 2048

#define LP_OFF 2L
#define ZQ_OFF (2L + 33554432L)
#define EM_OFF (33554434L + 8388608L)

// ws layout (floats)
#define WS_HIST 0
#define WS_CSUM 1024
#define WS_SSUM 2048
#define WS_MSUM 3072
#define WS_E8 4096              // bf16 e, 512 KB: [s][g][col] 16B units
#define WS_Z8G (4096 + 131072)  // bf16 z, 16 MB: [blk][oct][row] 16B units
#define WS_NEED_Z ((size_t)WS_Z8G * 4 + (size_t)NROW * KD * 2)

typedef __attribute__((ext_vector_type(8))) short bf16x8;
typedef __attribute__((ext_vector_type(4))) float f32x4;

__device__ __forceinline__ void gl_lds16(const void* g, void* l) {
  __builtin_amdgcn_global_load_lds(
      (const __attribute__((address_space(1))) void*)g,
      (__attribute__((address_space(3))) void*)l, 16, 0, 0);
}

__device__ __forceinline__ unsigned short f2bf(float x) {  // RNE
  unsigned u = __float_as_uint(x);
  unsigned r = ((u >> 16) & 1u) + 0x7FFFu;
  return (unsigned short)((u + r) >> 16);
}

__device__ __forceinline__ unsigned foldf(float v) {  // order-preserving
  unsigned b = __float_as_uint(v);
  return b ^ ((unsigned)((int)b >> 31) | 0x80000000u);
}
__device__ __forceinline__ float unfoldf(unsigned k) {
  unsigned s = (unsigned)((int)k >> 31);
  return __uint_as_float(k ^ (0x80000000u | (~s & 0x7FFFFFFFu)));
}

__device__ __forceinline__ int4 pack8(const float* p) {
  float4 a = *(const float4*)p;
  float4 b = *(const float4*)(p + 4);
  int4 pk;
  pk.x = f2bf(a.x) | ((unsigned)f2bf(a.y) << 16);
  pk.y = f2bf(a.z) | ((unsigned)f2bf(a.w) << 16);
  pk.z = f2bf(b.x) | ((unsigned)f2bf(b.y) << 16);
  pk.w = f2bf(b.z) | ((unsigned)f2bf(b.w) << 16);
  return pk;
}

// z8g unit t: blk=t>>10, oct=(t>>5)&31, row=t&31 -> z[blk*32+row][oct*8..+7]
// e8 unit t2: o=t2>>10 (k-oct), col=t2&1023 -> e[col][o*8..+7]  ([s][g][col])
__global__ __launch_bounds__(256) void tok_prep(
    const float* __restrict__ z, const float* __restrict__ cw,
    unsigned short* __restrict__ e8, unsigned short* __restrict__ z8g) {
  int t = blockIdx.x * 256 + threadIdx.x;
  if (t < 1048576) {
    int blk = t >> 10, oct = (t >> 5) & 31, row = t & 31;
    *(int4*)(z8g + ((size_t)t << 3)) =
        pack8(z + ((size_t)((blk << 5) + row) << 8) + (oct << 3));
    return;
  }
  int t2 = t - 1048576;
  if (t2 >= 32768) return;
  int o = t2 >> 10, n = t2 & 1023;
  *(int4*)(e8 + ((size_t)t2 << 3)) =
      pack8(cw + ((size_t)(1 + n) << 8) + (o << 3));
}

__global__ __launch_bounds__(TPB, 4) void tok_mfma(
    const float* __restrict__ z, const float* __restrict__ mask,
    const float* __restrict__ cw, const unsigned short* __restrict__ e8,
    const unsigned short* __restrict__ z8g, float* __restrict__ out,
    float* __restrict__ ws) {
  __shared__ __align__(16) unsigned short Bs[32768];  // 64 KB B step-tile
  __shared__ __align__(16) unsigned char apool[4736]; // epilogue overlays
  unsigned(*wkey)[2][33] = (unsigned(*)[2][33])apool;       // 2112
  float(*wsum)[33] = (float(*)[33])(apool + 2112);          // 1056
  float* lse_s = (float*)(apool + 3168);                    // 128
  float(*exv_s)[4] = (float(*)[4])(apool + 3296);           // 512
  int(*exi_s)[4] = (int(*)[4])(apool + 3808);               // 512
  int* argi = (int*)(apool + 4320);                         // 128
  float* cred = (float*)(apool + 4448);                     // 32
  float* sred = (float*)(apool + 4480);                     // 32

  const int tid = threadIdx.x;
  const int lane = tid & 63;
  const int w = tid >> 6;   // 0..7
  const int g = lane >> 4;  // 0..3
  const int lm = lane & 15;
  const int c0 = w << 7;  // wave's 128-col base
  const int n0 = blockIdx.x * BM;

  const bf16x8* Az = (const bf16x8*)z8g + ((size_t)blockIdx.x << 10);

  // ---- stage B step 0 (64 KB, 8 x 1KB-contig gl_lds16 per thread) ----
#pragma unroll
  for (int r = 0; r < 8; ++r)
    gl_lds16(e8 + (((r << 9) + tid) << 3), &Bs[((r << 9) + tid) << 3]);
  asm volatile("s_waitcnt vmcnt(0)" ::: "memory");
  __syncthreads();

  f32x4 accA[8], accB[8];
  const f32x4 zzero = {0.f, 0.f, 0.f, 0.f};
#pragma unroll
  for (int nt = 0; nt < 8; ++nt) { accA[nt] = zzero; accB[nt] = zzero; }

  bf16x8 a0 = Az[(g << 5) + lm];        // step-0 A frags (rows 0-15 / 16-31)
  bf16x8 a1 = Az[(g << 5) + 16 + lm];

  // ---- main loop: ds_read B + MFMA, re-stage via DMA, 2 barriers/step ----
#pragma unroll 1
  for (int s = 0; s < 8; ++s) {
    bf16x8 na0, na1;
    if (s < 7) {  // next-step A prefetch (2 loads, covered by MFMA phase)
      na0 = Az[((((s + 1) << 2) + g) << 5) + lm];
      na1 = Az[((((s + 1) << 2) + g) << 5) + 16 + lm];
    }
    const bf16x8* Bl = (const bf16x8*)&Bs[((g << 10) + c0 + lm) << 3];
#pragma unroll
    for (int nt = 0; nt < 8; ++nt) {
      bf16x8 b = Bl[nt << 4];
      accA[nt] = __builtin_amdgcn_mfma_f32_16x16x32_bf16(a0, b, accA[nt], 0, 0, 0);
      accB[nt] = __builtin_amdgcn_mfma_f32_16x16x32_bf16(a1, b, accB[nt], 0, 0, 0);
    }
    __syncthreads();  // all waves' B reads done before overwrite
    if (s < 7) {
#pragma unroll
      for (int r = 0; r < 8; ++r)
        gl_lds16(e8 + ((((s + 1) << 12) + (r << 9) + tid) << 3),
                 &Bs[((r << 9) + tid) << 3]);
      asm volatile("s_waitcnt vmcnt(0)" ::: "memory");
      __syncthreads();  // step s+1 tile ready
    }
    a0 = na0;
    a1 = na1;
  }

  // D layout: row = mt*16 + g*4 + j, col = c0 + nt*16 + lm (R7-verified)
  unsigned colpack[8];
#pragma unroll
  for (int nt = 0; nt < 8; ++nt)
    colpack[nt] = 1023u - (unsigned)(c0 + (nt << 4) + lm);

  // ---- phase1: per-wave top-2 keys + wave-local exp-sum ----
  auto phase1 = [&](f32x4(&ac)[8], int mt) {
#pragma unroll
    for (int j = 0; j < 4; ++j) {
      const int r = (mt << 4) + (g << 2) + j;
      unsigned cur[8];
#pragma unroll
      for (int nt = 0; nt < 8; ++nt)
        cur[nt] = (foldf(ac[nt][j]) & 0xFFFFFC00u) | colpack[nt];
      unsigned k1 = cur[0];
#pragma unroll
      for (int nt = 1; nt < 8; ++nt) k1 = k1 > cur[nt] ? k1 : cur[nt];
#pragma unroll
      for (int d = 1; d <= 8; d <<= 1) {
        unsigned o2 = __shfl_xor(k1, d);
        k1 = k1 > o2 ? k1 : o2;
      }
      const float mw = unfoldf(k1 & 0xFFFFFC00u);
      float sum = 0.f;
#pragma unroll
      for (int nt = 0; nt < 8; ++nt) sum += __expf(ac[nt][j] - mw);
#pragma unroll
      for (int d = 1; d <= 8; d <<= 1) sum += __shfl_xor(sum, d);
#pragma unroll
      for (int nt = 0; nt < 8; ++nt)
        if (cur[nt] == k1) cur[nt] = 0u;
      unsigned k2 = cur[0];
#pragma unroll
      for (int nt = 1; nt < 8; ++nt) k2 = k2 > cur[nt] ? k2 : cur[nt];
#pragma unroll
      for (int d = 1; d <= 8; d <<= 1) {
        unsigned o2 = __shfl_xor(k2, d);
        k2 = k2 > o2 ? k2 : o2;
      }
      if (lm == 0) {
        wkey[w][0][r] = k1;
        wkey[w][1][r] = k2;
        wsum[w][r] = sum;
      }
    }
  };
  phase1(accA, 0);
  phase1(accB, 1);
  __syncthreads();

  // ---- row stats: global top-4 + lse (32 threads) ----
  if (tid < 32) {
    const int r = tid;
    unsigned best[4] = {0u, 0u, 0u, 0u};
#pragma unroll
    for (int w2 = 0; w2 < 8; ++w2)
#pragma unroll
      for (int k = 0; k < 2; ++k) {
        unsigned x = wkey[w2][k][r];
#pragma unroll
        for (int q = 0; q < 4; ++q) {
          unsigned mx = x > best[q] ? x : best[q];
          unsigned mn = x > best[q] ? best[q] : x;
          best[q] = mx;
          x = mn;
        }
      }
    const float M = unfoldf(best[0] & 0xFFFFFC00u);
    float S = 0.f;
#pragma unroll
    for (int w2 = 0; w2 < 8; ++w2)
      S += wsum[w2][r] * __expf(unfoldf(wkey[w2][0][r] & 0xFFFFFC00u) - M);
    lse_s[r] = M + __logf(S);
#pragma unroll
    for (int q = 0; q < 4; ++q) exi_s[r][q] = (int)(1023u - (best[q] & 0x3FFu));
  }
  __syncthreads();

  // ---- E4B: exact fp32 dots (z & e from global; L2/L3-resident) ----
  {
    const int row = (w << 2) + (lane >> 4);
    const int cd = (lane >> 2) & 3;
    const int seg = lane & 3;  // 64-float segment
    const int cand = exi_s[row][cd];
    const float* er = cw + (size_t)(1 + cand) * KD + (seg << 6);
    const float* zr = z + (size_t)(n0 + row) * KD + (seg << 6);
    float s = 0.f;
#pragma unroll
    for (int i2 = 0; i2 < 16; ++i2) {
      float4 a4 = *(const float4*)(zr + (i2 << 2));
      float4 b4 = *(const float4*)(er + (i2 << 2));
      s += a4.x * b4.x + a4.y * b4.y + a4.z * b4.z + a4.w * b4.w;
    }
    s += __shfl_xor(s, 1);
    s += __shfl_xor(s, 2);
    if (seg == 0) exv_s[row][cd] = s;
  }
  __syncthreads();

  // ---- final argmax (exact, first-index tiebreak) + histogram ----
  if (tid < 32) {
    const int row = tid;
    float bv = exv_s[row][0];
    int bi = exi_s[row][0];
#pragma unroll
    for (int c = 1; c < 4; ++c) {
      float v = exv_s[row][c];
      int ci = exi_s[row][c];
      if (v > bv || (v == bv && ci < bi)) { bv = v; bi = ci; }
    }
    argi[row] = bi;
    atomicAdd(&ws[WS_HIST + bi], mask[n0 + row]);  // mask=1.0 adds: exact
  }
  __syncthreads();

  // ---- E5: losses (z/mask from global; keep e rows in regs for z_q) ----
  float csum = 0.f, ssum = 0.f;
  float4 evs[4];
  const bool has_prev = (n0 % TT) != 0;
#pragma unroll
  for (int i = 0; i < 4; ++i) {
    const int r = (i << 3) + w;
    const int c4 = lane << 2;
    const int idx = argi[r];
    const float4 ev = *(const float4*)&cw[(size_t)(1 + idx) * KD + c4];
    evs[i] = ev;
    const float4 zv = *(const float4*)&z[(size_t)(n0 + r) * KD + c4];
    const float mk = mask[n0 + r];
    float dx = zv.x - ev.x, dy = zv.y - ev.y, dz2 = zv.z - ev.z,
          dw = zv.w - ev.w;
    csum += mk * (dx * dx + dy * dy + dz2 * dz2 + dw * dw);
    if (r > 0 || has_prev) {
      const float4 pv = *(const float4*)&z[(size_t)(n0 + r - 1) * KD + c4];
      float ax = zv.x - pv.x, ay = zv.y - pv.y, az = zv.z - pv.z,
            aw = zv.w - pv.w;
      ssum += mk * (ax * ax + ay * ay + az * az + aw * aw);
    }
  }
#pragma unroll
  for (int d = 1; d <= 32; d <<= 1) {
    csum += __shfl_xor(csum, d);
    ssum += __shfl_xor(ssum, d);
  }
  if (lane == 0) { cred[w] = csum; sred[w] = ssum; }
  __syncthreads();
  if (tid == 0) {
    float cs = 0.f, ss2 = 0.f;
#pragma unroll
    for (int i = 0; i < 8; ++i) { cs += cred[i]; ss2 += sred[i]; }
    ws[WS_CSUM + blockIdx.x] = cs;
    ws[WS_SSUM + blockIdx.x] = ss2;
    float ms = 0.f;
    for (int r2 = 0; r2 < BM; ++r2) ms += mask[n0 + r2];
    ws[WS_MSUM + blockIdx.x] = ms;
  }

  // ---- stores dead-last: z_q then log_probs; no barriers after ----
#pragma unroll
  for (int i = 0; i < 4; ++i) {
    const int r = (i << 3) + w;
    *(float4*)&out[ZQ_OFF + (size_t)(n0 + r) * KD + (lane << 2)] = evs[i];
  }
  auto phase3 = [&](f32x4(&ac)[8], int mt) {
#pragma unroll
    for (int j = 0; j < 4; ++j) {
      const int r = (mt << 4) + (g << 2) + j;
      const float lse = lse_s[r];
      size_t base = LP_OFF + (size_t)(n0 + r) * VV;
#pragma unroll
      for (int nt = 0; nt < 8; ++nt)
        out[base + c0 + (nt << 4) + lm] = ac[nt][j] - lse;
    }
  };
  phase3(accA, 0);
  phase3(accB, 1);
}

// ---------- fp32 fallback if ws too small ----------
__global__ __launch_bounds__(256, 2) void tok_fb(
    const float* __restrict__ z, const float* __restrict__ mask,
    const float* __restrict__ cw, float* __restrict__ out,
    float* __restrict__ ws) {
  __shared__ __align__(16) float z_s[BM][KD];
  __shared__ int argi_s[BM];
  __shared__ float cred[4], sred[4];
  const int tid = threadIdx.x;
  const int lane = tid & 63;
  const int wave = tid >> 6;
  const int n0 = blockIdx.x * BM;
  const float* e = cw + KD;
#pragma unroll
  for (int i = 0; i < 8; ++i) {
    int seg = wave * 8 + i;
    gl_lds16(&z[(size_t)(n0 + seg) * KD + lane * 4], &z_s[seg][0]);
  }
  __syncthreads();
  float acc[8][16];
#pragma unroll
  for (int r = 0; r < 8; ++r)
#pragma unroll
    for (int m = 0; m < 16; ++m) acc[r][m] = 0.f;
#pragma unroll 1
  for (int i = 0; i < 64; ++i) {
    float4 ef[16];
#pragma unroll
    for (int m = 0; m < 16; ++m)
      ef[m] = *(const float4*)&e[(size_t)((m << 6) + lane) * KD + (i << 2)];
    float4 zf[8];
#pragma unroll
    for (int rr = 0; rr < 8; ++rr)
      zf[rr] = *(const float4*)&z_s[(wave << 3) + rr][i << 2];
#pragma unroll
    for (int m = 0; m < 16; ++m)
#pragma unroll
      for (int rr = 0; rr < 8; ++rr)
        acc[rr][m] += zf[rr].x * ef[m].x + zf[rr].y * ef[m].y +
                      zf[rr].z * ef[m].z + zf[rr].w * ef[m].w;
  }
  const int rowbase = wave << 3;
#pragma unroll
  for (int rr = 0; rr < 8; ++rr) {
    float mv = acc[rr][0];
    int mc = lane;
#pragma unroll
    for (int m = 1; m < 16; ++m) {
      float v = acc[rr][m];
      int c = (m << 6) + lane;
      bool tk = v > mv;
      mc = tk ? c : mc;
      mv = tk ? v : mv;
    }
#pragma unroll
    for (int d = 32; d >= 1; d >>= 1) {
      float ov = __shfl_xor(mv, d);
      int oc = __shfl_xor(mc, d);
      bool tk = (ov > mv) || (ov == mv && oc < mc);
      mv = tk ? ov : mv;
      mc = tk ? oc : mc;
    }
    float sum = 0.f;
#pragma unroll
    for (int m = 0; m < 16; ++m) sum += __expf(acc[rr][m] - mv);
#pragma unroll
    for (int d = 32; d >= 1; d >>= 1) sum += __shfl_xor(sum, d);
    float lse = mv + __logf(sum);
    size_t base = LP_OFF + (size_t)(n0 + rowbase + rr) * VV;
#pragma unroll
    for (int m = 0; m < 16; ++m) out[base + (m << 6) + lane] = acc[rr][m] - lse;
    if (lane == 0) {
      argi_s[rowbase + rr] = mc;
      atomicAdd(&ws[WS_HIST + mc], mask[n0 + rowbase + rr]);
    }
  }
  __syncthreads();
  float csum = 0.f, ssum = 0.f;
  const bool has_prev = (n0 % TT) != 0;
#pragma unroll
  for (int i = 0; i < 8; ++i) {
    int q = i * 256 + tid;
    int r = q >> 6;
    int c4 = (q & 63) << 2;
    int idx = argi_s[r];
    const float4 ev = *(const float4*)&e[(size_t)idx * KD + c4];
    const float4 zv = *(const float4*)&z_s[r][c4];
    *(float4*)&out[ZQ_OFF + (size_t)(n0 + r) * KD + c4] = ev;
    float mk = mask[n0 + r];
    float dx = zv.x - ev.x, dy = zv.y - ev.y, dz2 = zv.z - ev.z, dw = zv.w - ev.w;
    csum += mk * (dx * dx + dy * dy + dz2 * dz2 + dw * dw);
    if (r > 0) {
      const float4 pv = *(const float4*)&z_s[r - 1][c4];
      float ax = zv.x - pv.x, ay = zv.y - pv.y, az = zv.z - pv.z, aw = zv.w - pv.w;
      ssum += mk * (ax * ax + ay * ay + az * az + aw * aw);
    } else if (has_prev) {
      const float4 pv = *(const float4*)&z[(size_t)(n0 - 1) * KD + c4];
      float ax = zv.x - pv.x, ay = zv.y - pv.y, az = zv.z - pv.z, aw = zv.w - pv.w;
      ssum += mk * (ax * ax + ay * ay + az * az + aw * aw);
    }
  }
#pragma unroll
  for (int d = 32; d >= 1; d >>= 1) {
    csum += __shfl_xor(csum, d);
    ssum += __shfl_xor(ssum, d);
  }
  if (lane == 0) { cred[wave] = csum; sred[wave] = ssum; }
  __syncthreads();
  if (tid == 0) {
    ws[WS_CSUM + blockIdx.x] = cred[0] + cred[1] + cred[2] + cred[3];
    ws[WS_SSUM + blockIdx.x] = sred[0] + sred[1] + sred[2] + sred[3];
    float ms = 0.f;
    for (int r2 = 0; r2 < BM; ++r2) ms += mask[n0 + r2];
    ws[WS_MSUM + blockIdx.x] = ms;
  }
}

__global__ __launch_bounds__(1024) void tok_final(const float* __restrict__ ws,
                                                  float* __restrict__ out) {
  const int t = threadIdx.x;
  const int lane = t & 63, w = t >> 6;
  __shared__ float red[16];
  auto blockReduce = [&](float v) -> float {
#pragma unroll
    for (int d = 32; d >= 1; d >>= 1) v += __shfl_xor(v, d);
    __syncthreads();
    if (lane == 0) red[w] = v;
    __syncthreads();
    float s = 0.f;
#pragma unroll
    for (int i = 0; i < 16; ++i) s += red[i];
    return s;
  };
  float Mtot = blockReduce(ws[WS_MSUM + t]);
  float Ctot = blockReduce(ws[WS_CSUM + t]);
  float Stot = blockReduce(ws[WS_SSUM + t]);
  float prob = ws[WS_HIST + t] / Mtot;
  float psum = blockReduce(prob);
  out[EM_OFF + t] = prob / psum;
  if (t == 0) {
    float vc = Mtot * (float)KD;
    out[0] = Stot / vc;  // smoothness_loss
    out[1] = Ctot / vc;  // commitment_loss
  }
}

extern "C" void kernel_launch(void* const* d_in, const int* in_sizes, int n_in,
                              void* d_out, int out_size, void* d_ws,
                              size_t ws_size, hipStream_t stream) {
  const float* z = (const float*)d_in[0];
  const float* mask = (const float*)d_in[1];
  const float* cw = (const float*)d_in[2];
  float* out = (float*)d_out;
  float* ws = (float*)d_ws;
  hipMemsetAsync(ws, 0, 1024 * sizeof(float), stream);  // histogram zeros
  if (ws_size >= WS_NEED_Z) {
    unsigned short* e8 = (unsigned short*)(ws + WS_E8);
    unsigned short* z8g = (unsigned short*)(ws + WS_Z8G);
    tok_prep<<<4224, 256, 0, stream>>>(z, cw, e8, z8g);
    tok_mfma<<<NBLK, TPB, 0, stream>>>(z, mask, cw, e8, z8g, out, ws);
  } else {
    tok_fb<<<NBLK, 256, 0, stream>>>(z, mask, cw, out, ws);
  }
  tok_final<<<1, 1024, 0, stream>>>(ws, out);
}

// Round 9
// 117.840 us; speedup vs baseline: 1.3328x; 1.0429x over previous
//
#include <hip/hip_runtime.h>
#include <hip/hip_bf16.h>

#define TPB 512  // 8 waves
#define BM 32
#define NROW 32768
#define NBLK (NROW / BM)
#define VV 1024
#define KD 256
#define TT 2048

#define LP_OFF 2L
#define ZQ_OFF (2L + 33554432L)
#define EM_OFF (33554434L + 8388608L)

// ws layout (floats)
#define WS_HIST 0
#define WS_CSUM 1024
#define WS_SSUM 2048
#define WS_MSUM 3072
#define WS_E8 4096              // bf16 e, 512 KB: [s][w][g][c128] 16B units
#define WS_Z8G (4096 + 131072)  // bf16 z, 16 MB: [blk][oct][row] 16B units
#define WS_NEED_Z ((size_t)WS_Z8G * 4 + (size_t)NROW * KD * 2)

typedef __attribute__((ext_vector_type(8))) short bf16x8;
typedef __attribute__((ext_vector_type(4))) float f32x4;

__device__ __forceinline__ void gl_lds16(const void* g, void* l) {
  __builtin_amdgcn_global_load_lds(
      (const __attribute__((address_space(1))) void*)g,
      (__attribute__((address_space(3))) void*)l, 16, 0, 0);
}

__device__ __forceinline__ unsigned short f2bf(float x) {  // RNE
  unsigned u = __float_as_uint(x);
  unsigned r = ((u >> 16) & 1u) + 0x7FFFu;
  return (unsigned short)((u + r) >> 16);
}

__device__ __forceinline__ unsigned foldf(float v) {  // order-preserving
  unsigned b = __float_as_uint(v);
  return b ^ ((unsigned)((int)b >> 31) | 0x80000000u);
}
__device__ __forceinline__ float unfoldf(unsigned k) {
  unsigned s = (unsigned)((int)k >> 31);
  return __uint_as_float(k ^ (0x80000000u | (~s & 0x7FFFFFFFu)));
}

__device__ __forceinline__ int4 pack8(const float* p) {
  float4 a = *(const float4*)p;
  float4 b = *(const float4*)(p + 4);
  int4 pk;
  pk.x = f2bf(a.x) | ((unsigned)f2bf(a.y) << 16);
  pk.y = f2bf(a.z) | ((unsigned)f2bf(a.w) << 16);
  pk.z = f2bf(b.x) | ((unsigned)f2bf(b.y) << 16);
  pk.w = f2bf(b.z) | ((unsigned)f2bf(b.w) << 16);
  return pk;
}

// z8g unit t: blk=t>>10, oct=(t>>5)&31, row=t&31 -> z[blk*32+row][oct*8..+7]
// e8 unit t2 = (s<<12)+(w<<9)+(g<<7)+c : col n = w*128+c, oct o = s*4+g
//   -> per (step s, wave w) slice is 8 KB contiguous (wave-private DMA)
__global__ __launch_bounds__(256) void tok_prep(
    const float* __restrict__ z, const float* __restrict__ cw,
    unsigned short* __restrict__ e8, unsigned short* __restrict__ z8g) {
  int t = blockIdx.x * 256 + threadIdx.x;
  if (t < 1048576) {
    int blk = t >> 10, oct = (t >> 5) & 31, row = t & 31;
    *(int4*)(z8g + ((size_t)t << 3)) =
        pack8(z + ((size_t)((blk << 5) + row) << 8) + (oct << 3));
    return;
  }
  int t2 = t - 1048576;
  if (t2 >= 32768) return;
  int s = t2 >> 12, w = (t2 >> 9) & 7, g = (t2 >> 7) & 3, c = t2 & 127;
  int n = (w << 7) + c;   // column 0..1023
  int o = (s << 2) + g;   // k-oct 0..31
  *(int4*)(e8 + ((size_t)t2 << 3)) =
      pack8(cw + ((size_t)(1 + n) << 8) + (o << 3));
}

__global__ __launch_bounds__(TPB, 4) void tok_mfma(
    const float* __restrict__ z, const float* __restrict__ mask,
    const float* __restrict__ cw, const unsigned short* __restrict__ e8,
    const unsigned short* __restrict__ z8g, float* __restrict__ out,
    float* __restrict__ ws) {
  __shared__ __align__(16) unsigned short Bs[32768];  // 64 KB: [w][g][c128]
  __shared__ __align__(16) unsigned char apool[4736]; // epilogue overlays
  unsigned(*wkey)[2][33] = (unsigned(*)[2][33])apool;       // 2112
  float(*wsum)[33] = (float(*)[33])(apool + 2112);          // 1056
  float* lse_s = (float*)(apool + 3168);                    // 128
  float(*exv_s)[4] = (float(*)[4])(apool + 3296);           // 512
  int(*exi_s)[4] = (int(*)[4])(apool + 3808);               // 512
  int* argi = (int*)(apool + 4320);                         // 128
  float* cred = (float*)(apool + 4448);                     // 32
  float* sred = (float*)(apool + 4480);                     // 32

  const int tid = threadIdx.x;
  const int lane = tid & 63;
  const int w = tid >> 6;   // 0..7
  const int g = lane >> 4;  // 0..3
  const int lm = lane & 15;
  const int c0 = w << 7;  // wave's 128-col base
  const int n0 = blockIdx.x * BM;

  const bf16x8* Az = (const bf16x8*)z8g + ((size_t)blockIdx.x << 10);

  // ---- wave-private stage of step-0 slice (8 KB, 8 x 1KB DMA) ----
#pragma unroll
  for (int r = 0; r < 8; ++r)
    gl_lds16(e8 + (((w << 9) + (r << 6) + lane) << 3),
             &Bs[(((w << 9) + (r << 6)) + lane) << 3]);

  f32x4 accA[8], accB[8];
  const f32x4 zzero = {0.f, 0.f, 0.f, 0.f};
#pragma unroll
  for (int nt = 0; nt < 8; ++nt) { accA[nt] = zzero; accB[nt] = zzero; }

  bf16x8 a0 = Az[(g << 5) + lm];   // step-0 A frags (rows 0-15 / 16-31)
  bf16x8 a1 = Az[(g << 5) + 16 + lm];
  const bf16x8* Bl = (const bf16x8*)&Bs[((w << 9) + (g << 7) + lm) << 3];

  // ---- barrier-free K-loop: wave-local vmcnt/lgkmcnt ordering only ----
#pragma unroll 1
  for (int s = 0; s < 8; ++s) {
    asm volatile("s_waitcnt vmcnt(0)" ::: "memory");  // slice s + A(s) landed
    bf16x8 na0, na1;
    if (s < 7) {  // next-step A prefetch (latency hidden under MFMAs)
      na0 = Az[((((s + 1) << 2) + g) << 5) + lm];
      na1 = Az[((((s + 1) << 2) + g) << 5) + 16 + lm];
    }
#pragma unroll
    for (int nt = 0; nt < 8; ++nt) {
      bf16x8 b = Bl[nt << 4];
      accA[nt] = __builtin_amdgcn_mfma_f32_16x16x32_bf16(a0, b, accA[nt], 0, 0, 0);
      accB[nt] = __builtin_amdgcn_mfma_f32_16x16x32_bf16(a1, b, accB[nt], 0, 0, 0);
    }
    asm volatile("s_waitcnt lgkmcnt(0)" ::: "memory");  // slice-s reads done
    if (s < 7) {  // refill own slice for s+1 (overlaps epilogue of this iter)
#pragma unroll
      for (int r = 0; r < 8; ++r)
        gl_lds16(e8 + ((((s + 1) << 12) + (w << 9) + (r << 6) + lane) << 3),
                 &Bs[(((w << 9) + (r << 6)) + lane) << 3]);
    }
    a0 = na0;
    a1 = na1;
  }

  // D layout: row = mt*16 + g*4 + j, col = c0 + nt*16 + lm (R7/R8-verified)
  unsigned colpack[8];
#pragma unroll
  for (int nt = 0; nt < 8; ++nt)
    colpack[nt] = 1023u - (unsigned)(c0 + (nt << 4) + lm);

  // ---- phase1: per-wave top-2 keys + wave-local exp-sum ----
  auto phase1 = [&](f32x4(&ac)[8], int mt) {
#pragma unroll
    for (int j = 0; j < 4; ++j) {
      const int r = (mt << 4) + (g << 2) + j;
      unsigned cur[8];
#pragma unroll
      for (int nt = 0; nt < 8; ++nt)
        cur[nt] = (foldf(ac[nt][j]) & 0xFFFFFC00u) | colpack[nt];
      unsigned k1 = cur[0];
#pragma unroll
      for (int nt = 1; nt < 8; ++nt) k1 = k1 > cur[nt] ? k1 : cur[nt];
#pragma unroll
      for (int d = 1; d <= 8; d <<= 1) {
        unsigned o2 = __shfl_xor(k1, d);
        k1 = k1 > o2 ? k1 : o2;
      }
      const float mw = unfoldf(k1 & 0xFFFFFC00u);
      float sum = 0.f;
#pragma unroll
      for (int nt = 0; nt < 8; ++nt) sum += __expf(ac[nt][j] - mw);
#pragma unroll
      for (int d = 1; d <= 8; d <<= 1) sum += __shfl_xor(sum, d);
#pragma unroll
      for (int nt = 0; nt < 8; ++nt)
        if (cur[nt] == k1) cur[nt] = 0u;
      unsigned k2 = cur[0];
#pragma unroll
      for (int nt = 1; nt < 8; ++nt) k2 = k2 > cur[nt] ? k2 : cur[nt];
#pragma unroll
      for (int d = 1; d <= 8; d <<= 1) {
        unsigned o2 = __shfl_xor(k2, d);
        k2 = k2 > o2 ? k2 : o2;
      }
      if (lm == 0) {
        wkey[w][0][r] = k1;
        wkey[w][1][r] = k2;
        wsum[w][r] = sum;
      }
    }
  };
  phase1(accA, 0);
  phase1(accB, 1);
  __syncthreads();

  // ---- row stats: global top-4 + lse (32 threads) ----
  if (tid < 32) {
    const int r = tid;
    unsigned best[4] = {0u, 0u, 0u, 0u};
#pragma unroll
    for (int w2 = 0; w2 < 8; ++w2)
#pragma unroll
      for (int k = 0; k < 2; ++k) {
        unsigned x = wkey[w2][k][r];
#pragma unroll
        for (int q = 0; q < 4; ++q) {
          unsigned mx = x > best[q] ? x : best[q];
          unsigned mn = x > best[q] ? best[q] : x;
          best[q] = mx;
          x = mn;
        }
      }
    const float M = unfoldf(best[0] & 0xFFFFFC00u);
    float S = 0.f;
#pragma unroll
    for (int w2 = 0; w2 < 8; ++w2)
      S += wsum[w2][r] * __expf(unfoldf(wkey[w2][0][r] & 0xFFFFFC00u) - M);
    lse_s[r] = M + __logf(S);
#pragma unroll
    for (int q = 0; q < 4; ++q) exi_s[r][q] = (int)(1023u - (best[q] & 0x3FFu));
  }
  __syncthreads();

  // ---- E4B: exact fp32 dots (z & e from global; L2/L3-resident) ----
  {
    const int row = (w << 2) + (lane >> 4);
    const int cd = (lane >> 2) & 3;
    const int seg = lane & 3;  // 64-float segment
    const int cand = exi_s[row][cd];
    const float* er = cw + (size_t)(1 + cand) * KD + (seg << 6);
    const float* zr = z + (size_t)(n0 + row) * KD + (seg << 6);
    float s = 0.f;
#pragma unroll
    for (int i2 = 0; i2 < 16; ++i2) {
      float4 a4 = *(const float4*)(zr + (i2 << 2));
      float4 b4 = *(const float4*)(er + (i2 << 2));
      s += a4.x * b4.x + a4.y * b4.y + a4.z * b4.z + a4.w * b4.w;
    }
    s += __shfl_xor(s, 1);
    s += __shfl_xor(s, 2);
    if (seg == 0) exv_s[row][cd] = s;
  }
  __syncthreads();

  // ---- final argmax (exact, first-index tiebreak) + histogram ----
  if (tid < 32) {
    const int row = tid;
    float bv = exv_s[row][0];
    int bi = exi_s[row][0];
#pragma unroll
    for (int c = 1; c < 4; ++c) {
      float v = exv_s[row][c];
      int ci = exi_s[row][c];
      if (v > bv || (v == bv && ci < bi)) { bv = v; bi = ci; }
    }
    argi[row] = bi;
    atomicAdd(&ws[WS_HIST + bi], mask[n0 + row]);  // mask=1.0 adds: exact
  }
  __syncthreads();

  // ---- E5: losses (z/mask from global; keep e rows in regs for z_q) ----
  float csum = 0.f, ssum = 0.f;
  float4 evs[4];
  const bool has_prev = (n0 % TT) != 0;
#pragma unroll
  for (int i = 0; i < 4; ++i) {
    const int r = (i << 3) + w;
    const int c4 = lane << 2;
    const int idx = argi[r];
    const float4 ev = *(const float4*)&cw[(size_t)(1 + idx) * KD + c4];
    evs[i] = ev;
    const float4 zv = *(const float4*)&z[(size_t)(n0 + r) * KD + c4];
    const float mk = mask[n0 + r];
    float dx = zv.x - ev.x, dy = zv.y - ev.y, dz2 = zv.z - ev.z,
          dw = zv.w - ev.w;
    csum += mk * (dx * dx + dy * dy + dz2 * dz2 + dw * dw);
    if (r > 0 || has_prev) {
      const float4 pv = *(const float4*)&z[(size_t)(n0 + r - 1) * KD + c4];
      float ax = zv.x - pv.x, ay = zv.y - pv.y, az = zv.z - pv.z,
            aw = zv.w - pv.w;
      ssum += mk * (ax * ax + ay * ay + az * az + aw * aw);
    }
  }
#pragma unroll
  for (int d = 1; d <= 32; d <<= 1) {
    csum += __shfl_xor(csum, d);
    ssum += __shfl_xor(ssum, d);
  }
  if (lane == 0) { cred[w] = csum; sred[w] = ssum; }
  __syncthreads();
  if (tid == 0) {
    float cs = 0.f, ss2 = 0.f;
#pragma unroll
    for (int i = 0; i < 8; ++i) { cs += cred[i]; ss2 += sred[i]; }
    ws[WS_CSUM + blockIdx.x] = cs;
    ws[WS_SSUM + blockIdx.x] = ss2;
    float ms = 0.f;
    for (int r2 = 0; r2 < BM; ++r2) ms += mask[n0 + r2];
    ws[WS_MSUM + blockIdx.x] = ms;
  }

  // ---- stores dead-last: z_q then log_probs; no barriers after ----
#pragma unroll
  for (int i = 0; i < 4; ++i) {
    const int r = (i << 3) + w;
    *(float4*)&out[ZQ_OFF + (size_t)(n0 + r) * KD + (lane << 2)] = evs[i];
  }
  auto phase3 = [&](f32x4(&ac)[8], int mt) {
#pragma unroll
    for (int j = 0; j < 4; ++j) {
      const int r = (mt << 4) + (g << 2) + j;
      const float lse = lse_s[r];
      size_t base = LP_OFF + (size_t)(n0 + r) * VV;
#pragma unroll
      for (int nt = 0; nt < 8; ++nt)
        out[base + c0 + (nt << 4) + lm] = ac[nt][j] - lse;
    }
  };
  phase3(accA, 0);
  phase3(accB, 1);
}

// ---------- fp32 fallback if ws too small ----------
__global__ __launch_bounds__(256, 2) void tok_fb(
    const float* __restrict__ z, const float* __restrict__ mask,
    const float* __restrict__ cw, float* __restrict__ out,
    float* __restrict__ ws) {
  __shared__ __align__(16) float z_s[BM][KD];
  __shared__ int argi_s[BM];
  __shared__ float cred[4], sred[4];
  const int tid = threadIdx.x;
  const int lane = tid & 63;
  const int wave = tid >> 6;
  const int n0 = blockIdx.x * BM;
  const float* e = cw + KD;
#pragma unroll
  for (int i = 0; i < 8; ++i) {
    int seg = wave * 8 + i;
    gl_lds16(&z[(size_t)(n0 + seg) * KD + lane * 4], &z_s[seg][0]);
  }
  __syncthreads();
  float acc[8][16];
#pragma unroll
  for (int r = 0; r < 8; ++r)
#pragma unroll
    for (int m = 0; m < 16; ++m) acc[r][m] = 0.f;
#pragma unroll 1
  for (int i = 0; i < 64; ++i) {
    float4 ef[16];
#pragma unroll
    for (int m = 0; m < 16; ++m)
      ef[m] = *(const float4*)&e[(size_t)((m << 6) + lane) * KD + (i << 2)];
    float4 zf[8];
#pragma unroll
    for (int rr = 0; rr < 8; ++rr)
      zf[rr] = *(const float4*)&z_s[(wave << 3) + rr][i << 2];
#pragma unroll
    for (int m = 0; m < 16; ++m)
#pragma unroll
      for (int rr = 0; rr < 8; ++rr)
        acc[rr][m] += zf[rr].x * ef[m].x + zf[rr].y * ef[m].y +
                      zf[rr].z * ef[m].z + zf[rr].w * ef[m].w;
  }
  const int rowbase = wave << 3;
#pragma unroll
  for (int rr = 0; rr < 8; ++rr) {
    float mv = acc[rr][0];
    int mc = lane;
#pragma unroll
    for (int m = 1; m < 16; ++m) {
      float v = acc[rr][m];
      int c = (m << 6) + lane;
      bool tk = v > mv;
      mc = tk ? c : mc;
      mv = tk ? v : mv;
    }
#pragma unroll
    for (int d = 32; d >= 1; d >>= 1) {
      float ov = __shfl_xor(mv, d);
      int oc = __shfl_xor(mc, d);
      bool tk = (ov > mv) || (ov == mv && oc < mc);
      mv = tk ? ov : mv;
      mc = tk ? oc : mc;
    }
    float sum = 0.f;
#pragma unroll
    for (int m = 0; m < 16; ++m) sum += __expf(acc[rr][m] - mv);
#pragma unroll
    for (int d = 32; d >= 1; d >>= 1) sum += __shfl_xor(sum, d);
    float lse = mv + __logf(sum);
    size_t base = LP_OFF + (size_t)(n0 + rowbase + rr) * VV;
#pragma unroll
    for (int m = 0; m < 16; ++m) out[base + (m << 6) + lane] = acc[rr][m] - lse;
    if (lane == 0) {
      argi_s[rowbase + rr] = mc;
      atomicAdd(&ws[WS_HIST + mc], mask[n0 + rowbase + rr]);
    }
  }
  __syncthreads();
  float csum = 0.f, ssum = 0.f;
  const bool has_prev = (n0 % TT) != 0;
#pragma unroll
  for (int i = 0; i < 8; ++i) {
    int q = i * 256 + tid;
    int r = q >> 6;
    int c4 = (q & 63) << 2;
    int idx = argi_s[r];
    const float4 ev = *(const float4*)&e[(size_t)idx * KD + c4];
    const float4 zv = *(const float4*)&z_s[r][c4];
    *(float4*)&out[ZQ_OFF + (size_t)(n0 + r) * KD + c4] = ev;
    float mk = mask[n0 + r];
    float dx = zv.x - ev.x, dy = zv.y - ev.y, dz2 = zv.z - ev.z, dw = zv.w - ev.w;
    csum += mk * (dx * dx + dy * dy + dz2 * dz2 + dw * dw);
    if (r > 0) {
      const float4 pv = *(const float4*)&z_s[r - 1][c4];
      float ax = zv.x - pv.x, ay = zv.y - pv.y, az = zv.z - pv.z, aw = zv.w - pv.w;
      ssum += mk * (ax * ax + ay * ay + az * az + aw * aw);
    } else if (has_prev) {
      const float4 pv = *(const float4*)&z[(size_t)(n0 - 1) * KD + c4];
      float ax = zv.x - pv.x, ay = zv.y - pv.y, az = zv.z - pv.z, aw = zv.w - pv.w;
      ssum += mk * (ax * ax + ay * ay + az * az + aw * aw);
    }
  }
#pragma unroll
  for (int d = 32; d >= 1; d >>= 1) {
    csum += __shfl_xor(csum, d);
    ssum += __shfl_xor(ssum, d);
  }
  if (lane == 0) { cred[wave] = csum; sred[wave] = ssum; }
  __syncthreads();
  if (tid == 0) {
    ws[WS_CSUM + blockIdx.x] = cred[0] + cred[1] + cred[2] + cred[3];
    ws[WS_SSUM + blockIdx.x] = sred[0] + sred[1] + sred[2] + sred[3];
    float ms = 0.f;
    for (int r2 = 0; r2 < BM; ++r2) ms += mask[n0 + r2];
    ws[WS_MSUM + blockIdx.x] = ms;
  }
}

__global__ __launch_bounds__(1024) void tok_final(const float* __restrict__ ws,
                                                  float* __restrict__ out) {
  const int t = threadIdx.x;
  const int lane = t & 63, w = t >> 6;
  __shared__ float red[16];
  auto blockReduce = [&](float v) -> float {
#pragma unroll
    for (int d = 32; d >= 1; d >>= 1) v += __shfl_xor(v, d);
    __syncthreads();
    if (lane == 0) red[w] = v;
    __syncthreads();
    float s = 0.f;
#pragma unroll
    for (int i = 0; i < 16; ++i) s += red[i];
    return s;
  };
  float Mtot = blockReduce(ws[WS_MSUM + t]);
  float Ctot = blockReduce(ws[WS_CSUM + t]);
  float Stot = blockReduce(ws[WS_SSUM + t]);
  float prob = ws[WS_HIST + t] / Mtot;
  float psum = blockReduce(prob);
  out[EM_OFF + t] = prob / psum;
  if (t == 0) {
    float vc = Mtot * (float)KD;
    out[0] = Stot / vc;  // smoothness_loss
    out[1] = Ctot / vc;  // commitment_loss
  }
}

extern "C" void kernel_launch(void* const* d_in, const int* in_sizes, int n_in,
                              void* d_out, int out_size, void* d_ws,
                              size_t ws_size, hipStream_t stream) {
  const float* z = (const float*)d_in[0];
  const float* mask = (const float*)d_in[1];
  const float* cw = (const float*)d_in[2];
  float* out = (float*)d_out;
  float* ws = (float*)d_ws;
  hipMemsetAsync(ws, 0, 1024 * sizeof(float), stream);  // histogram zeros
  if (ws_size >= WS_NEED_Z) {
    unsigned short* e8 = (unsigned short*)(ws + WS_E8);
    unsigned short* z8g = (unsigned short*)(ws + WS_Z8G);
    tok_prep<<<4224, 256, 0, stream>>>(z, cw, e8, z8g);
    tok_mfma<<<NBLK, TPB, 0, stream>>>(z, mask, cw, e8, z8g, out, ws);
  } else {
    tok_fb<<<NBLK, 256, 0, stream>>>(z, mask, cw, out, ws);
  }
  tok_final<<<1, 1024, 0, stream>>>(ws, out);
}